// Round 2
// baseline (73.477 us; speedup 1.0000x reference)
//
#include <hip/hip_runtime.h>

// out[b,o] = x@W1 + x^T W2[:,:,o] x + bias
// Quadratic part as GEMM: T = X(512x784) @ W2v(784x7840), W2v = W+7840 row-major,
// then quad[b,o] = sum_j x[b,j] * T[b, j*10+o]  (fused into GEMM epilogue).
// GEMM: 64x80 block tile, 4 waves (16x80 each), BK=64, double-buffered
// global_load_lds staging (linear dest + pre-swizzled source, XOR-swizzled reads).

#define D_IN 784
#define N_COL 7840
#define KP 832          // K padded to multiple of 64 (832 = 13*64)
#define M_B 512
#define OUTN 10
#define NBX 98          // N_COL / 80
#define WS_NEED ((size_t)2 * (M_B * KP + (size_t)N_COL * KP) + (size_t)NBX * M_B * OUTN * 4)

typedef __attribute__((ext_vector_type(4))) float f32x4;
typedef __attribute__((ext_vector_type(8))) __bf16 bf16x8;

__device__ __forceinline__ unsigned short f2bf(float f) {
  unsigned u = __builtin_bit_cast(unsigned, f);
  u += 0x7FFFu + ((u >> 16) & 1u);
  return (unsigned short)(u >> 16);
}

__device__ __forceinline__ void gld16(const void* g, void* l) {
  __builtin_amdgcn_global_load_lds((const __attribute__((address_space(1))) void*)g,
                                   (__attribute__((address_space(3))) void*)l, 16, 0, 0);
}

// ---- prep: x (512x784 f32) -> xb (512x832 bf16, zero-padded K) ----
__global__ __launch_bounds__(256) void conv_x_kernel(const float* __restrict__ x,
                                                     unsigned short* __restrict__ xb) {
  int t = blockIdx.x * 256 + threadIdx.x;
  int b = t / 208;
  int c4 = (t - b * 208) * 4;
  ushort4 u;
  u.x = (c4 + 0 < D_IN) ? f2bf(x[(size_t)b * D_IN + c4 + 0]) : (unsigned short)0;
  u.y = (c4 + 1 < D_IN) ? f2bf(x[(size_t)b * D_IN + c4 + 1]) : (unsigned short)0;
  u.z = (c4 + 2 < D_IN) ? f2bf(x[(size_t)b * D_IN + c4 + 2]) : (unsigned short)0;
  u.w = (c4 + 3 < D_IN) ? f2bf(x[(size_t)b * D_IN + c4 + 3]) : (unsigned short)0;
  *(ushort4*)(xb + (size_t)b * KP + c4) = u;
}

// ---- prep: W2v (784x7840 f32, row-major) -> Wt (7840x832 bf16) transposed ----
__global__ __launch_bounds__(256) void transpose_w_kernel(const float* __restrict__ W2v,
                                                          unsigned short* __restrict__ Wt) {
  __shared__ float tile[32][33];
  int c0 = blockIdx.x * 32;
  int k0 = blockIdx.y * 32;
  int tx = threadIdx.x;
  int ty = threadIdx.y;
#pragma unroll
  for (int q = 0; q < 4; ++q) {
    int ky = ty + 8 * q;
    int k = k0 + ky;
    tile[ky][tx] = (k < D_IN) ? W2v[(size_t)k * N_COL + (c0 + tx)] : 0.f;
  }
  __syncthreads();
#pragma unroll
  for (int q = 0; q < 4; ++q) {
    int cy = ty + 8 * q;
    Wt[(size_t)(c0 + cy) * KP + (k0 + tx)] = f2bf(tile[tx][cy]);
  }
}

// ---- linear part + bias: out[b,:] = x[b,:] @ W1 + bias ----
__global__ __launch_bounds__(256) void init_out_kernel(const float* __restrict__ x,
                                                       const float* __restrict__ W,
                                                       const float* __restrict__ bias,
                                                       float* __restrict__ out) {
  int b = blockIdx.x;
  int t = threadIdx.x;
  __shared__ float part[OUTN];
  if (t < OUTN) part[t] = bias[t];
  __syncthreads();
  float acc[OUTN];
#pragma unroll
  for (int o = 0; o < OUTN; ++o) acc[o] = 0.f;
  for (int i = t; i < D_IN; i += 256) {
    float xv = x[(size_t)b * D_IN + i];
#pragma unroll
    for (int o = 0; o < OUTN; ++o) acc[o] += xv * W[i * OUTN + o];
  }
#pragma unroll
  for (int o = 0; o < OUTN; ++o) {
    float v = acc[o];
#pragma unroll
    for (int s = 32; s > 0; s >>= 1) v += __shfl_down(v, s);
    if ((t & 63) == 0) atomicAdd(&part[o], v);
  }
  __syncthreads();
  if (t < OUTN) out[(size_t)b * OUTN + t] = part[t];
}

// ---- main GEMM + fused quad epilogue ----
// A tile 64x64(bf16)=8KB @ off 0, B tile 80x64(bf16)=10KB @ off 8192, 2 buffers.
// LDS byte layout per row: row*128 + (kchunk ^ (row&7))*16  (XOR swizzle).
// global_load_lds writes LINEAR (chunk c at byte c*16); source pre-swizzled so
// reads with the XOR retrieve the right data (rule: both-sides-or-neither).
template <int USE_WS>
__global__ __launch_bounds__(256) void gemm_quad_kernel(const unsigned short* __restrict__ xb,
                                                        const unsigned short* __restrict__ Wt,
                                                        const float* __restrict__ x,
                                                        float* __restrict__ dst) {
  __shared__ char smem[2][18432];
  __shared__ float xs[512];                   // x[64 rows][8 j-cols of this block]
  const int tid = threadIdx.x;
  const int w = tid >> 6, l = tid & 63;
  const int lr = l & 15, lh = l >> 4;
  const int bn0 = blockIdx.x * 80;
  const int bm0 = blockIdx.y * 64;
  const int j00 = blockIdx.x * 8;             // 80 cols == j in [8bx, 8bx+8), o=0..9

  // stage xs (read in epilogue only; main-loop barriers cover the hazard)
  for (int i = tid; i < 512; i += 256) {
    int r = i >> 3, jj = i & 7;
    xs[i] = x[(size_t)(bm0 + r) * D_IN + j00 + jj];
  }

  f32x4 acc[5];
#pragma unroll
  for (int nt = 0; nt < 5; ++nt) acc[nt] = (f32x4){0.f, 0.f, 0.f, 0.f};

  // stage one K-tile into smem[buf]: 18 x 1KB wave-instructions (A:8, B:10)
  auto stage = [&](int buf, int kt) {
    for (int i = w; i < 18; i += 4) {
      int isB = (i >= 8) ? 1 : 0;
      int cb = isB ? (i - 8) : i;
      int c = cb * 64 + l;
      int row = c >> 3, k16 = c & 7;
      const unsigned short* src = isB
          ? (Wt + (size_t)(bn0 + row) * KP + kt * 64 + (k16 ^ (row & 7)) * 8)
          : (xb + (size_t)(bm0 + row) * KP + kt * 64 + (k16 ^ (row & 7)) * 8);
      char* d = &smem[buf][(isB ? 8192 : 0) + cb * 1024];
      gld16(src, d);
    }
  };

  stage(0, 0);
  __syncthreads();
  int cur = 0;
  for (int kt = 0; kt < KP / 64; ++kt) {
    if (kt < KP / 64 - 1) stage(cur ^ 1, kt + 1);
    const char* sm = smem[cur];
#pragma unroll
    for (int kk = 0; kk < 2; ++kk) {
      int arow = w * 16 + lr;
      int akc = kk * 4 + lh;                  // k-chunk 0..7
      bf16x8 a = *(const bf16x8*)(sm + arow * 128 + ((akc ^ (arow & 7)) << 4));
      bf16x8 b[5];
#pragma unroll
      for (int nt = 0; nt < 5; ++nt) {
        int col = nt * 16 + lr;
        b[nt] = *(const bf16x8*)(sm + 8192 + col * 128 + ((akc ^ (col & 7)) << 4));
      }
#pragma unroll
      for (int nt = 0; nt < 5; ++nt)
        acc[nt] = __builtin_amdgcn_mfma_f32_16x16x32_bf16(a, b[nt], acc[nt], 0, 0, 0);
    }
    __syncthreads();                          // drains vmcnt(0): next tile ready
    cur ^= 1;
  }

  // epilogue: quad partial for this block's 80 cols; part aliases smem (post-barrier)
  float* part = (float*)&smem[0][0];          // [64][10]
  for (int i = tid; i < 64 * OUTN; i += 256) part[i] = 0.f;
  __syncthreads();
#pragma unroll
  for (int nt = 0; nt < 5; ++nt) {
    int gc = bn0 + nt * 16 + lr;
    int j = gc / 10;
    int o = gc - j * 10;
    int jj = j - j00;
#pragma unroll
    for (int r = 0; r < 4; ++r) {
      int rr = w * 16 + lh * 4 + r;           // C/D: col=lane&15, row=(lane>>4)*4+reg
      atomicAdd(&part[rr * OUTN + o], acc[nt][r] * xs[rr * 8 + jj]);
    }
  }
  __syncthreads();
  if (USE_WS) {
    float* wp = dst + (size_t)blockIdx.x * (M_B * OUTN) + bm0 * OUTN;
    for (int i = tid; i < 64 * OUTN; i += 256) wp[i] = part[i];
  } else {
    for (int i = tid; i < 64 * OUTN; i += 256) atomicAdd(&dst[bm0 * OUTN + i], part[i]);
  }
}

// ---- sum the 98 per-colblock partials into out ----
__global__ __launch_bounds__(256) void reduce_kernel(const float* __restrict__ ws,
                                                     float* __restrict__ out) {
  int i = blockIdx.x * 256 + threadIdx.x;     // 5120
  if (i < M_B * OUTN) {
    float s = 0.f;
    for (int c = 0; c < NBX; ++c) s += ws[(size_t)c * (M_B * OUTN) + i];
    out[i] += s;
  }
}

extern "C" void kernel_launch(void* const* d_in, const int* in_sizes, int n_in,
                              void* d_out, int out_size, void* d_ws, size_t ws_size,
                              hipStream_t stream) {
  const float* x = (const float*)d_in[0];
  const float* W = (const float*)d_in[1];
  const float* bias = (const float*)d_in[2];
  float* out = (float*)d_out;

  unsigned short* xb = (unsigned short*)d_ws;            // 512*832 bf16
  unsigned short* Wt = xb + (size_t)M_B * KP;            // 7840*832 bf16
  float* wsp = (float*)(Wt + (size_t)N_COL * KP);        // 98*512*10 f32 partials

  conv_x_kernel<<<(M_B * (KP / 4)) / 256, 256, 0, stream>>>(x, xb);
  transpose_w_kernel<<<dim3(N_COL / 32, KP / 32), dim3(32, 8), 0, stream>>>(W + D_IN * OUTN, Wt);
  init_out_kernel<<<M_B, 256, 0, stream>>>(x, W, bias, out);

  if (ws_size >= WS_NEED) {
    gemm_quad_kernel<1><<<dim3(NBX, M_B / 64), 256, 0, stream>>>(xb, Wt, x, wsp);
    reduce_kernel<<<(M_B * OUTN + 255) / 256, 256, 0, stream>>>(wsp, out);
  } else {
    gemm_quad_kernel<0><<<dim3(NBX, M_B / 64), 256, 0, stream>>>(xb, Wt, x, out);
  }
}